// Round 4
// baseline (293.102 us; speedup 1.0000x reference)
//
#include <hip/hip_runtime.h>
#include <cstddef>
#include <cstdint>

// Problem constants (B,T,D fixed by the reference).
#define B_ 8
#define T_ 4096
#define D_ 1024
#define M_ (B_*T_)        // 32768 rows
#define K_ 1024
#define NC 32             // scan chunks per sequence
#define CL 128            // steps per chunk

// GEMM tile config: 256x128 output tile, dual-B (r and i), BK=64, 8 waves.
#define BM 256
#define BN 128

typedef __bf16 bf16x8 __attribute__((ext_vector_type(8)));
typedef float  f32x4  __attribute__((ext_vector_type(4)));

__device__ __forceinline__ void gload_lds16(const __bf16* g, __bf16* l) {
    __builtin_amdgcn_global_load_lds(
        (const __attribute__((address_space(1))) void*)g,
        (__attribute__((address_space(3))) void*)l, 16, 0, 0);
}

__device__ __forceinline__ float bfbits2f(uint32_t hi16_as_low) {
    return __builtin_bit_cast(float, hi16_as_low);
}

// ---------------------------------------------------------------------------
// cvt_swz: fp32 [rows][1024] -> bf16, reorganized into 16 k-chunks of 64 cols,
// each row 128B, XOR-swizzled within the row: byte ^= (row&7)<<4.
// Inverse-swizzled source so linear global_load_lds lands the swizzle in LDS
// and ds_read applies the same XOR (G21). Zero bank conflicts verified (R2/R3).
// ---------------------------------------------------------------------------
__global__ __launch_bounds__(256) void cvt_swz(const float* __restrict__ src,
                                               __bf16* __restrict__ dst, int rows)
{
    const int g  = blockIdx.x * 256 + threadIdx.x;   // rows*128 threads
    const int r  = g >> 7;
    const int k0 = (g & 127) << 3;                   // 8 elems per thread
    const int kc = k0 >> 6;
    const int jj = k0 & 63;
    const float4 v0 = *reinterpret_cast<const float4*>(src + (size_t)r * 1024 + k0);
    const float4 v1 = *reinterpret_cast<const float4*>(src + (size_t)r * 1024 + k0 + 4);
    bf16x8 s;
    s[0]=(__bf16)v0.x; s[1]=(__bf16)v0.y; s[2]=(__bf16)v0.z; s[3]=(__bf16)v0.w;
    s[4]=(__bf16)v1.x; s[5]=(__bf16)v1.y; s[6]=(__bf16)v1.z; s[7]=(__bf16)v1.w;
    const uint32_t inrow = (uint32_t)(r * 128 + (jj << 1)) ^ (uint32_t)((r & 7) << 4);
    const size_t byteoff = (size_t)kc * ((size_t)rows * 128) + inrow;
    *reinterpret_cast<bf16x8*>(reinterpret_cast<char*>(dst) + byteoff) = s;
}

// ---------------------------------------------------------------------------
// K1: fused dual-GEMM + slim gate epilogue, 4-phase counted-vmcnt pipeline
// (T3+T4+T5). zr = x@Wa^T + ba, zi = x@Wx^T + bx; r=sig(zr), i=sig(zi);
// e = 8*r*log2(sig(lambda)); stores packed dword {lo: bf16(e), hi: bf16(i*x)}.
// a/gate/gx reconstruction deferred to the (BW-bound, VALU-free) scan kernels.
// ---------------------------------------------------------------------------
__global__ __launch_bounds__(512, 1) void rg_gemm_gate(
    const __bf16* __restrict__ Xsw, const __bf16* __restrict__ Wasw,
    const __bf16* __restrict__ Wxsw, const float* __restrict__ Ba,
    const float* __restrict__ Bx, const float* __restrict__ LL,
    uint32_t* __restrict__ EIX)
{
    __shared__ __bf16 Al [2][BM * 64];   // 64 KiB
    __shared__ __bf16 Brs[2][BN * 64];   // 32 KiB
    __shared__ __bf16 Bis[2][BN * 64];   // 32 KiB

    const int tid  = threadIdx.x;
    const int lane = tid & 63;
    const int w    = tid >> 6;           // 8 waves: 4M x 2N
    const int wr   = (w >> 1) * 64;
    const int wc   = (w & 1) * 64;

    // XCD swizzle (1024 blocks, %8==0): n-tile fastest within each XCD.
    const int bid  = blockIdx.x;
    const int wgid = (bid & 7) * 128 + (bid >> 3);
    const int n0   = (wgid & 7) << 7;    // 8 n-tiles
    const int m0   = (wgid >> 3) << 8;   // 128 m-tiles

    const int lrow = lane & 15;
    const int lkb  = (lane >> 4) << 4;   // byte offset of k-fragment in row

    f32x4 accr[4][4] = {};
    f32x4 acci[4][4] = {};

    // Per-wave stage = 8 global_load_lds (A:4, Br:2, Bi:2), 1 KiB each.
    auto STAGE = [&](int buf, int kc) {
        const size_t cbA = (size_t)kc * ((size_t)M_ * 64) + (size_t)m0 * 64;
        const size_t cbB = (size_t)kc * (1024 * 64) + (size_t)n0 * 64;
        #pragma unroll
        for (int c = 0; c < 4; ++c) {
            const int j = (c * 8 + w) * 512;
            gload_lds16(Xsw + cbA + j + lane * 8, &Al[buf][j]);
        }
        #pragma unroll
        for (int c = 0; c < 2; ++c) {
            const int j = (c * 8 + w) * 512;
            gload_lds16(Wasw + cbB + j + lane * 8, &Brs[buf][j]);
            gload_lds16(Wxsw + cbB + j + lane * 8, &Bis[buf][j]);
        }
    };

    auto READ_A = [&](const char* Ab, int ks, bf16x8* af) {
        #pragma unroll
        for (int mi = 0; mi < 4; ++mi) {
            const int ra = wr + mi * 16 + lrow;
            const uint32_t bo = (uint32_t)(ra * 128 + ks * 64 + lkb)
                              ^ (uint32_t)((ra & 7) << 4);
            af[mi] = *reinterpret_cast<const bf16x8*>(Ab + bo);
        }
    };
    auto READ_B = [&](const char* Bb, int ks, bf16x8* bf) {
        #pragma unroll
        for (int ni = 0; ni < 4; ++ni) {
            const int rb = wc + ni * 16 + lrow;
            const uint32_t bo = (uint32_t)(rb * 128 + ks * 64 + lkb)
                              ^ (uint32_t)((rb & 7) << 4);
            bf[ni] = *reinterpret_cast<const bf16x8*>(Bb + bo);
        }
    };
    auto MFMA16 = [&](const bf16x8* af, const bf16x8* bf, f32x4 (*acc)[4]) {
        __builtin_amdgcn_s_setprio(1);
        #pragma unroll
        for (int mi = 0; mi < 4; ++mi) {
            #pragma unroll
            for (int ni = 0; ni < 4; ++ni) {
                acc[mi][ni] = __builtin_amdgcn_mfma_f32_16x16x32_bf16(
                    af[mi], bf[ni], acc[mi][ni], 0, 0, 0);
            }
        }
        __builtin_amdgcn_s_setprio(0);
    };

    STAGE(0, 0);
    for (int kc = 0; kc < 16; ++kc) {
        const int cur = kc & 1;
        // Tile open: issue next tile's 8 loads, then wait for THIS tile's 8
        // (issued one tile ago) with the new 8 still in flight (T4: never 0).
        if (kc < 15) {
            STAGE(cur ^ 1, kc + 1);
            asm volatile("s_waitcnt vmcnt(8)" ::: "memory");
        } else {
            asm volatile("s_waitcnt vmcnt(0)" ::: "memory");
        }
        __builtin_amdgcn_s_barrier();   // publish gl_lds across waves

        const char* Ab = reinterpret_cast<const char*>(Al[cur]);
        const char* Rb = reinterpret_cast<const char*>(Brs[cur]);
        const char* Ib = reinterpret_cast<const char*>(Bis[cur]);

        bf16x8 af[4], brf[4], bif[4];
        // ph0: A(ks0) + Br(ks0) reads -> 16 MFMA accr
        READ_A(Ab, 0, af);
        READ_B(Rb, 0, brf);
        MFMA16(af, brf, accr);
        __builtin_amdgcn_s_barrier();
        // ph1: Bi(ks0) reads -> 16 MFMA acci
        READ_B(Ib, 0, bif);
        MFMA16(af, bif, acci);
        __builtin_amdgcn_s_barrier();
        // ph2: A(ks1) + Br(ks1) reads -> 16 MFMA accr
        READ_A(Ab, 1, af);
        READ_B(Rb, 1, brf);
        MFMA16(af, brf, accr);
        __builtin_amdgcn_s_barrier();
        // ph3: Bi(ks1) reads -> 16 MFMA acci
        READ_B(Ib, 1, bif);
        MFMA16(af, bif, acci);
        __builtin_amdgcn_s_barrier();   // all reads of buf[cur] done before restage
    }

    // ---- epilogue: C/D layout col = lane&15, row = (lane>>4)*4 + j ----
    const int rbase = m0 + wr + ((lane >> 4) << 2);
    const int cbase = n0 + wc + lrow;
    #pragma unroll
    for (int ni = 0; ni < 4; ++ni) {
        const int col = cbase + ni * 16;
        const float lam = LL[col];
        const float l2s = -log2f(1.0f + __expf(-lam));  // log2(sigmoid(lambda))
        const float bav = Ba[col];
        const float bxv = Bx[col];
        const int   kcx = col >> 6;
        const uint32_t colin = (uint32_t)((col & 63) << 1);
        const char* xbase = reinterpret_cast<const char*>(Xsw)
                          + (size_t)kcx * ((size_t)M_ * 128);
        #pragma unroll
        for (int mi = 0; mi < 4; ++mi) {
            #pragma unroll
            for (int j = 0; j < 4; ++j) {
                const int row = rbase + mi * 16 + j;
                const float zr = accr[mi][ni][j] + bav;
                const float zi = acci[mi][ni][j] + bxv;
                const float rv = 1.0f / (1.0f + __expf(-zr));
                const float iv = 1.0f / (1.0f + __expf(-zi));
                const float ee = 8.0f * rv * l2s;       // log2(a)
                const uint32_t inrow = ((uint32_t)(row * 128) + colin)
                                     ^ (uint32_t)((row & 7) << 4);
                const uint16_t xb = *reinterpret_cast<const uint16_t*>(xbase + inrow);
                const float xv  = bfbits2f((uint32_t)xb << 16);
                const float ixv = iv * xv;
                const uint16_t ebits  = __builtin_bit_cast(uint16_t, (__bf16)ee);
                const uint16_t ixbits = __builtin_bit_cast(uint16_t, (__bf16)ixv);
                EIX[(size_t)row * D_ + col] = (uint32_t)ebits | ((uint32_t)ixbits << 16);
            }
        }
    }
}

// ---------------------------------------------------------------------------
// K2: per-chunk summaries: P = prod a = 2^(sum e), hend = local scan from 0.
// ---------------------------------------------------------------------------
__global__ __launch_bounds__(256) void rg_scan_chunks(
    const uint32_t* __restrict__ EIX, float* __restrict__ P, float* __restrict__ HE)
{
    const int g = blockIdx.x * 256 + threadIdx.x;   // < B*NC*D = 262144
    const int d = g & (D_ - 1);
    const int c = (g >> 10) & (NC - 1);
    const int b = g >> 15;
    const size_t base = ((size_t)(b * T_ + c * CL)) * D_ + d;

    float h = 0.0f;
    float se = 0.0f;
    #pragma unroll 8
    for (int t = 0; t < CL; ++t) {
        const uint32_t u = EIX[base + (size_t)t * D_];
        const float e  = bfbits2f(u << 16);
        const float ix = bfbits2f(u & 0xffff0000u);
        const float a  = exp2f(e);
        const float gate = sqrtf(fmaxf((1.0f - a) * (1.0f + a), 1e-6f));
        h = fmaf(a, h, gate * ix);
        se += e;
    }
    const int sidx = (b * NC + c) * D_ + d;
    P[sidx]  = exp2f(se);
    HE[sidx] = h;
}

// ---------------------------------------------------------------------------
// K3: sequential combine over NC chunks per (b,d); seeds with h0.
// ---------------------------------------------------------------------------
__global__ __launch_bounds__(256) void rg_combine(
    const float* __restrict__ P, const float* __restrict__ HE,
    const float* __restrict__ H0, float* __restrict__ CI,
    float* __restrict__ HF)
{
    const int g = blockIdx.x * 256 + threadIdx.x;   // < B*D = 8192
    const int d = g & (D_ - 1);
    const int b = g >> 10;
    float carry = H0[g];
    #pragma unroll
    for (int c = 0; c < NC; ++c) {
        const int sidx = (b * NC + c) * D_ + d;
        CI[sidx] = carry;
        carry = fmaf(P[sidx], carry, HE[sidx]);
    }
    HF[g] = carry;
}

// ---------------------------------------------------------------------------
// K4: final intra-chunk scan with correct carry; writes h_t to OUT (write-only).
// ---------------------------------------------------------------------------
__global__ __launch_bounds__(256) void rg_scan_final(
    const uint32_t* __restrict__ EIX, const float* __restrict__ CI,
    float* __restrict__ OUT)
{
    const int g = blockIdx.x * 256 + threadIdx.x;   // < B*NC*D
    const int d = g & (D_ - 1);
    const int c = (g >> 10) & (NC - 1);
    const int b = g >> 15;
    const size_t base = ((size_t)(b * T_ + c * CL)) * D_ + d;

    float h = CI[(b * NC + c) * D_ + d];
    #pragma unroll 8
    for (int t = 0; t < CL; ++t) {
        const size_t idx = base + (size_t)t * D_;
        const uint32_t u = EIX[idx];
        const float e  = bfbits2f(u << 16);
        const float ix = bfbits2f(u & 0xffff0000u);
        const float a  = exp2f(e);
        const float gate = sqrtf(fmaxf((1.0f - a) * (1.0f + a), 1e-6f));
        h = fmaf(a, h, gate * ix);
        OUT[idx] = h;
    }
}

// ---------------------------------------------------------------------------
extern "C" void kernel_launch(void* const* d_in, const int* in_sizes, int n_in,
                              void* d_out, int out_size, void* d_ws, size_t ws_size,
                              hipStream_t stream)
{
    (void)in_sizes; (void)n_in; (void)out_size; (void)ws_size;
    const float* X  = (const float*)d_in[0];
    const float* H0 = (const float*)d_in[1];
    const float* Wa = (const float*)d_in[2];
    const float* Ba = (const float*)d_in[3];
    const float* Wx = (const float*)d_in[4];
    const float* Bx = (const float*)d_in[5];
    const float* LL = (const float*)d_in[6];

    // d_out doubles as scratch for the bf16-converted operands (dead before K4
    // rewrites every output element):
    //   [0,64MB)    Xsw   (bf16, swizzled k-chunked)
    //   [64,66MB)   Wasw  [66,68MB) Wxsw
    char* ob = (char*)d_out;
    __bf16* Xsw  = (__bf16*)ob;
    __bf16* Wasw = (__bf16*)(ob + ((size_t)M_ * K_ * 2));
    __bf16* Wxsw = (__bf16*)(ob + ((size_t)M_ * K_ * 2) + (size_t)K_ * D_ * 2);
    float*  OUT  = (float*)d_out;
    float*  HFINAL = OUT + (size_t)M_ * D_;    // h_final after outputs

    // ws: EIX (uint32, 128MB) | P | HE | CI (1MB each)  = 131 MB
    char* ws = (char*)d_ws;
    uint32_t* EIX = (uint32_t*)ws;
    float* P  = (float*)(ws + (size_t)M_ * D_ * 4);
    float* HE = P  + (size_t)B_ * NC * D_;
    float* CI = HE + (size_t)B_ * NC * D_;

    cvt_swz<<<dim3(M_ / 2), dim3(256), 0, stream>>>(X, Xsw, M_);
    cvt_swz<<<dim3(512), dim3(256), 0, stream>>>(Wa, Wasw, 1024);
    cvt_swz<<<dim3(512), dim3(256), 0, stream>>>(Wx, Wxsw, 1024);

    rg_gemm_gate<<<dim3((M_/BM) * (D_/BN)), dim3(512), 0, stream>>>(
        Xsw, Wasw, Wxsw, Ba, Bx, LL, EIX);

    rg_scan_chunks<<<dim3(B_ * NC * D_ / 256), dim3(256), 0, stream>>>(EIX, P, HE);
    rg_combine<<<dim3(B_ * D_ / 256), dim3(256), 0, stream>>>(P, HE, H0, CI, HFINAL);
    rg_scan_final<<<dim3(B_ * NC * D_ / 256), dim3(256), 0, stream>>>(EIX, CI, OUT);
}

// Round 5
// 285.668 us; speedup vs baseline: 1.0260x; 1.0260x over previous
//
#include <hip/hip_runtime.h>
#include <cstddef>
#include <cstdint>

// Problem constants (B,T,D fixed by the reference).
#define B_ 8
#define T_ 4096
#define D_ 1024
#define M_ (B_*T_)        // 32768 rows
#define K_ 1024
#define NC 32             // scan chunks per sequence
#define CL 128            // steps per chunk

// GEMM tile config: 256x128 output tile, dual-B (r and i), BK=64, 8 waves.
#define BM 256
#define BN 128

typedef __bf16 bf16x8 __attribute__((ext_vector_type(8)));
typedef float  f32x4  __attribute__((ext_vector_type(4)));

__device__ __forceinline__ void gload_lds16(const __bf16* g, __bf16* l) {
    __builtin_amdgcn_global_load_lds(
        (const __attribute__((address_space(1))) void*)g,
        (__attribute__((address_space(3))) void*)l, 16, 0, 0);
}

__device__ __forceinline__ float bfbits2f(uint32_t hi16_as_low) {
    return __builtin_bit_cast(float, hi16_as_low);
}

// ---------------------------------------------------------------------------
// cvt_swz: fp32 [rows][1024] -> bf16, reorganized into 16 k-chunks of 64 cols,
// each row 128B, XOR-swizzled within the row: byte ^= (row&7)<<4.
// Inverse-swizzled source so linear global_load_lds lands the swizzle in LDS
// and ds_read applies the same XOR (G21). Zero bank conflicts verified (R2/R3).
// ---------------------------------------------------------------------------
__global__ __launch_bounds__(256) void cvt_swz(const float* __restrict__ src,
                                               __bf16* __restrict__ dst, int rows)
{
    const int g  = blockIdx.x * 256 + threadIdx.x;   // rows*128 threads
    const int r  = g >> 7;
    const int k0 = (g & 127) << 3;                   // 8 elems per thread
    const int kc = k0 >> 6;
    const int jj = k0 & 63;
    const float4 v0 = *reinterpret_cast<const float4*>(src + (size_t)r * 1024 + k0);
    const float4 v1 = *reinterpret_cast<const float4*>(src + (size_t)r * 1024 + k0 + 4);
    bf16x8 s;
    s[0]=(__bf16)v0.x; s[1]=(__bf16)v0.y; s[2]=(__bf16)v0.z; s[3]=(__bf16)v0.w;
    s[4]=(__bf16)v1.x; s[5]=(__bf16)v1.y; s[6]=(__bf16)v1.z; s[7]=(__bf16)v1.w;
    const uint32_t inrow = (uint32_t)(r * 128 + (jj << 1)) ^ (uint32_t)((r & 7) << 4);
    const size_t byteoff = (size_t)kc * ((size_t)rows * 128) + inrow;
    *reinterpret_cast<bf16x8*>(reinterpret_cast<char*>(dst) + byteoff) = s;
}

// ---------------------------------------------------------------------------
// K1: fused dual-GEMM + slim gate epilogue. 4-phase-per-K-tile pipeline,
// m201-template ordering: {reads-for-this-phase; 2 stage issues; [vmcnt(2)];
// barrier; lgkmcnt(0); sched_barrier; setprio(1); 16 MFMA; setprio(0);
// barrier}. Counted vmcnt only at ph0/ph3 (never 0 mid-loop).
// ---------------------------------------------------------------------------
__global__ __launch_bounds__(512, 1) void rg_gemm_gate(
    const __bf16* __restrict__ Xsw, const __bf16* __restrict__ Wasw,
    const __bf16* __restrict__ Wxsw, const float* __restrict__ Ba,
    const float* __restrict__ Bx, const float* __restrict__ LL,
    uint32_t* __restrict__ EIX)
{
    __shared__ __bf16 Al [2][BM * 64];   // 64 KiB
    __shared__ __bf16 Brs[2][BN * 64];   // 32 KiB
    __shared__ __bf16 Bis[2][BN * 64];   // 32 KiB

    const int tid  = threadIdx.x;
    const int lane = tid & 63;
    const int w    = tid >> 6;           // 8 waves: 4M x 2N
    const int wr   = (w >> 1) * 64;
    const int wc   = (w & 1) * 64;

    // XCD swizzle (1024 blocks, %8==0): n-tile fastest within each XCD.
    const int bid  = blockIdx.x;
    const int wgid = (bid & 7) * 128 + (bid >> 3);
    const int n0   = (wgid & 7) << 7;    // 8 n-tiles
    const int m0   = (wgid >> 3) << 8;   // 128 m-tiles

    const int lrow = lane & 15;
    const int lkb  = (lane >> 4) << 4;   // byte offset of k-fragment in row

    f32x4 accr[4][4] = {};
    f32x4 acci[4][4] = {};

    // Stage pieces: per chunk a wave issues A:4, Br:2, Bi:2 gl_lds (1KiB each),
    // split 2 per phase in order A,A,Br,Bi so vmcnt(2) ledgers work out.
    auto STAGE_A = [&](int buf, int kc, int half) {
        const size_t cbA = (size_t)kc * ((size_t)M_ * 64) + (size_t)m0 * 64;
        #pragma unroll
        for (int c = half * 2; c < half * 2 + 2; ++c) {
            const int j = (c * 8 + w) * 512;
            gload_lds16(Xsw + cbA + j + lane * 8, &Al[buf][j]);
        }
    };
    auto STAGE_BR = [&](int buf, int kc) {
        const size_t cbB = (size_t)kc * (1024 * 64) + (size_t)n0 * 64;
        #pragma unroll
        for (int c = 0; c < 2; ++c) {
            const int j = (c * 8 + w) * 512;
            gload_lds16(Wasw + cbB + j + lane * 8, &Brs[buf][j]);
        }
    };
    auto STAGE_BI = [&](int buf, int kc) {
        const size_t cbB = (size_t)kc * (1024 * 64) + (size_t)n0 * 64;
        #pragma unroll
        for (int c = 0; c < 2; ++c) {
            const int j = (c * 8 + w) * 512;
            gload_lds16(Wxsw + cbB + j + lane * 8, &Bis[buf][j]);
        }
    };

    auto READ_A = [&](const char* Ab, int ks, bf16x8* af) {
        #pragma unroll
        for (int mi = 0; mi < 4; ++mi) {
            const int ra = wr + mi * 16 + lrow;
            const uint32_t bo = (uint32_t)(ra * 128 + ks * 64 + lkb)
                              ^ (uint32_t)((ra & 7) << 4);
            af[mi] = *reinterpret_cast<const bf16x8*>(Ab + bo);
        }
    };
    auto READ_B = [&](const char* Bb, int ks, bf16x8* bf) {
        #pragma unroll
        for (int ni = 0; ni < 4; ++ni) {
            const int rb = wc + ni * 16 + lrow;
            const uint32_t bo = (uint32_t)(rb * 128 + ks * 64 + lkb)
                              ^ (uint32_t)((rb & 7) << 4);
            bf[ni] = *reinterpret_cast<const bf16x8*>(Bb + bo);
        }
    };
    auto MFMA16 = [&](const bf16x8* af, const bf16x8* bf, f32x4 (*acc)[4]) {
        __builtin_amdgcn_s_setprio(1);
        #pragma unroll
        for (int mi = 0; mi < 4; ++mi) {
            #pragma unroll
            for (int ni = 0; ni < 4; ++ni) {
                acc[mi][ni] = __builtin_amdgcn_mfma_f32_16x16x32_bf16(
                    af[mi], bf[ni], acc[mi][ni], 0, 0, 0);
            }
        }
        __builtin_amdgcn_s_setprio(0);
    };

    // Prologue: stage chunk 0 fully, drain, publish.
    STAGE_A(0, 0, 0); STAGE_A(0, 0, 1); STAGE_BR(0, 0); STAGE_BI(0, 0);
    asm volatile("s_waitcnt vmcnt(0)" ::: "memory");
    __builtin_amdgcn_s_barrier();

    for (int kc = 0; kc < 16; ++kc) {
        const int cur = kc & 1;
        const char* Ab = reinterpret_cast<const char*>(Al[cur]);
        const char* Rb = reinterpret_cast<const char*>(Brs[cur]);
        const char* Ib = reinterpret_cast<const char*>(Bis[cur]);
        bf16x8 af0[4], af1[4], brf[4], bif[4];

        // ph0: c0 = accr += A(ks0) x Br(ks0)
        READ_A(Ab, 0, af0);
        READ_B(Rb, 0, brf);
        if (kc < 15) {
            STAGE_A(cur ^ 1, kc + 1, 0);
            asm volatile("s_waitcnt vmcnt(2)" ::: "memory");  // old Bi landed; new A in flight
        } else {
            asm volatile("s_waitcnt vmcnt(0)" ::: "memory");
        }
        __builtin_amdgcn_s_barrier();
        asm volatile("s_waitcnt lgkmcnt(0)" ::: "memory");
        __builtin_amdgcn_sched_barrier(0);
        MFMA16(af0, brf, accr);
        __builtin_amdgcn_s_barrier();

        // ph1: c1 = acci += A(ks0) x Bi(ks0)
        READ_B(Ib, 0, bif);
        if (kc < 15) STAGE_A(cur ^ 1, kc + 1, 1);
        __builtin_amdgcn_s_barrier();
        asm volatile("s_waitcnt lgkmcnt(0)" ::: "memory");
        __builtin_amdgcn_sched_barrier(0);
        MFMA16(af0, bif, acci);
        __builtin_amdgcn_s_barrier();

        // ph2: c2 = accr += A(ks1) x Br(ks1)
        READ_A(Ab, 1, af1);
        READ_B(Rb, 1, brf);
        if (kc < 15) STAGE_BR(cur ^ 1, kc + 1);
        __builtin_amdgcn_s_barrier();
        asm volatile("s_waitcnt lgkmcnt(0)" ::: "memory");
        __builtin_amdgcn_sched_barrier(0);
        MFMA16(af1, brf, accr);
        __builtin_amdgcn_s_barrier();

        // ph3: c3 = acci += A(ks1) x Bi(ks1)
        READ_B(Ib, 1, bif);
        if (kc < 15) {
            STAGE_BI(cur ^ 1, kc + 1);
            asm volatile("s_waitcnt vmcnt(2)" ::: "memory");  // next A+Br landed; Bi in flight
        }
        __builtin_amdgcn_s_barrier();
        asm volatile("s_waitcnt lgkmcnt(0)" ::: "memory");
        __builtin_amdgcn_sched_barrier(0);
        MFMA16(af1, bif, acci);
        __builtin_amdgcn_s_barrier();
    }

    // ---- epilogue: C/D layout col = lane&15, row = (lane>>4)*4 + j ----
    const int rbase = m0 + wr + ((lane >> 4) << 2);
    const int cbase = n0 + wc + lrow;
    #pragma unroll
    for (int ni = 0; ni < 4; ++ni) {
        const int col = cbase + ni * 16;
        const float lam = LL[col];
        const float l2s = -log2f(1.0f + __expf(-lam));  // log2(sigmoid(lambda))
        const float bav = Ba[col];
        const float bxv = Bx[col];
        const int   kcx = col >> 6;
        const uint32_t colin = (uint32_t)((col & 63) << 1);
        const char* xbase = reinterpret_cast<const char*>(Xsw)
                          + (size_t)kcx * ((size_t)M_ * 128);
        #pragma unroll
        for (int mi = 0; mi < 4; ++mi) {
            #pragma unroll
            for (int j = 0; j < 4; ++j) {
                const int row = rbase + mi * 16 + j;
                const float zr = accr[mi][ni][j] + bav;
                const float zi = acci[mi][ni][j] + bxv;
                const float rv = 1.0f / (1.0f + __expf(-zr));
                const float iv = 1.0f / (1.0f + __expf(-zi));
                const float ee = 8.0f * rv * l2s;       // log2(a)
                const uint32_t inrow = ((uint32_t)(row * 128) + colin)
                                     ^ (uint32_t)((row & 7) << 4);
                const uint16_t xb = *reinterpret_cast<const uint16_t*>(xbase + inrow);
                const float xv  = bfbits2f((uint32_t)xb << 16);
                const float ixv = iv * xv;
                const uint16_t ebits  = __builtin_bit_cast(uint16_t, (__bf16)ee);
                const uint16_t ixbits = __builtin_bit_cast(uint16_t, (__bf16)ixv);
                EIX[(size_t)row * D_ + col] = (uint32_t)ebits | ((uint32_t)ixbits << 16);
            }
        }
    }
}

// ---------------------------------------------------------------------------
// K2: per-chunk summaries: P = prod a = 2^(sum e), hend = local scan from 0.
// ---------------------------------------------------------------------------
__global__ __launch_bounds__(256) void rg_scan_chunks(
    const uint32_t* __restrict__ EIX, float* __restrict__ P, float* __restrict__ HE)
{
    const int g = blockIdx.x * 256 + threadIdx.x;   // < B*NC*D = 262144
    const int d = g & (D_ - 1);
    const int c = (g >> 10) & (NC - 1);
    const int b = g >> 15;
    const size_t base = ((size_t)(b * T_ + c * CL)) * D_ + d;

    float h = 0.0f;
    float se = 0.0f;
    #pragma unroll 8
    for (int t = 0; t < CL; ++t) {
        const uint32_t u = EIX[base + (size_t)t * D_];
        const float e  = bfbits2f(u << 16);
        const float ix = bfbits2f(u & 0xffff0000u);
        const float a  = exp2f(e);
        const float gate = sqrtf(fmaxf((1.0f - a) * (1.0f + a), 1e-6f));
        h = fmaf(a, h, gate * ix);
        se += e;
    }
    const int sidx = (b * NC + c) * D_ + d;
    P[sidx]  = exp2f(se);
    HE[sidx] = h;
}

// ---------------------------------------------------------------------------
// K3: sequential combine over NC chunks per (b,d); seeds with h0.
// ---------------------------------------------------------------------------
__global__ __launch_bounds__(256) void rg_combine(
    const float* __restrict__ P, const float* __restrict__ HE,
    const float* __restrict__ H0, float* __restrict__ CI,
    float* __restrict__ HF)
{
    const int g = blockIdx.x * 256 + threadIdx.x;   // < B*D = 8192
    const int d = g & (D_ - 1);
    const int b = g >> 10;
    float carry = H0[g];
    #pragma unroll
    for (int c = 0; c < NC; ++c) {
        const int sidx = (b * NC + c) * D_ + d;
        CI[sidx] = carry;
        carry = fmaf(P[sidx], carry, HE[sidx]);
    }
    HF[g] = carry;
}

// ---------------------------------------------------------------------------
// K4: final intra-chunk scan with correct carry; writes h_t to OUT (write-only).
// ---------------------------------------------------------------------------
__global__ __launch_bounds__(256) void rg_scan_final(
    const uint32_t* __restrict__ EIX, const float* __restrict__ CI,
    float* __restrict__ OUT)
{
    const int g = blockIdx.x * 256 + threadIdx.x;   // < B*NC*D
    const int d = g & (D_ - 1);
    const int c = (g >> 10) & (NC - 1);
    const int b = g >> 15;
    const size_t base = ((size_t)(b * T_ + c * CL)) * D_ + d;

    float h = CI[(b * NC + c) * D_ + d];
    #pragma unroll 8
    for (int t = 0; t < CL; ++t) {
        const size_t idx = base + (size_t)t * D_;
        const uint32_t u = EIX[idx];
        const float e  = bfbits2f(u << 16);
        const float ix = bfbits2f(u & 0xffff0000u);
        const float a  = exp2f(e);
        const float gate = sqrtf(fmaxf((1.0f - a) * (1.0f + a), 1e-6f));
        h = fmaf(a, h, gate * ix);
        OUT[idx] = h;
    }
}

// ---------------------------------------------------------------------------
extern "C" void kernel_launch(void* const* d_in, const int* in_sizes, int n_in,
                              void* d_out, int out_size, void* d_ws, size_t ws_size,
                              hipStream_t stream)
{
    (void)in_sizes; (void)n_in; (void)out_size; (void)ws_size;
    const float* X  = (const float*)d_in[0];
    const float* H0 = (const float*)d_in[1];
    const float* Wa = (const float*)d_in[2];
    const float* Ba = (const float*)d_in[3];
    const float* Wx = (const float*)d_in[4];
    const float* Bx = (const float*)d_in[5];
    const float* LL = (const float*)d_in[6];

    // d_out doubles as scratch for the bf16-converted operands (dead before K4
    // rewrites every output element):
    //   [0,64MB)    Xsw   (bf16, swizzled k-chunked)
    //   [64,66MB)   Wasw  [66,68MB) Wxsw
    char* ob = (char*)d_out;
    __bf16* Xsw  = (__bf16*)ob;
    __bf16* Wasw = (__bf16*)(ob + ((size_t)M_ * K_ * 2));
    __bf16* Wxsw = (__bf16*)(ob + ((size_t)M_ * K_ * 2) + (size_t)K_ * D_ * 2);
    float*  OUT  = (float*)d_out;
    float*  HFINAL = OUT + (size_t)M_ * D_;    // h_final after outputs

    // ws: EIX (uint32, 128MB) | P | HE | CI (1MB each)  = 131 MB
    char* ws = (char*)d_ws;
    uint32_t* EIX = (uint32_t*)ws;
    float* P  = (float*)(ws + (size_t)M_ * D_ * 4);
    float* HE = P  + (size_t)B_ * NC * D_;
    float* CI = HE + (size_t)B_ * NC * D_;

    cvt_swz<<<dim3(M_ / 2), dim3(256), 0, stream>>>(X, Xsw, M_);
    cvt_swz<<<dim3(512), dim3(256), 0, stream>>>(Wa, Wasw, 1024);
    cvt_swz<<<dim3(512), dim3(256), 0, stream>>>(Wx, Wxsw, 1024);

    rg_gemm_gate<<<dim3((M_/BM) * (D_/BN)), dim3(512), 0, stream>>>(
        Xsw, Wasw, Wxsw, Ba, Bx, LL, EIX);

    rg_scan_chunks<<<dim3(B_ * NC * D_ / 256), dim3(256), 0, stream>>>(EIX, P, HE);
    rg_combine<<<dim3(B_ * D_ / 256), dim3(256), 0, stream>>>(P, HE, H0, CI, HFINAL);
    rg_scan_final<<<dim3(B_ * NC * D_ / 256), dim3(256), 0, stream>>>(EIX, CI, OUT);
}